// Round 3
// baseline (461.855 us; speedup 1.0000x reference)
//
#include <hip/hip_runtime.h>
#include <hip/hip_bf16.h>
#include <cstdint>

#define D_DIM 768
#define BM 128
#define BN 256
#define BK 128   // one K-tile = 2 k-steps of the K=64 MFMA

typedef int   intx8    __attribute__((ext_vector_type(8)));
typedef float floatx16 __attribute__((ext_vector_type(16)));

#define SCALE_ONE 0x7F7F7F7F  // E8M0 127 = 2^0 in every byte

// ---- helpers ----------------------------------------------------------------

__device__ inline void lds_load16(const void* g, void* lds) {
  __builtin_amdgcn_global_load_lds(
      (const __attribute__((address_space(1))) unsigned int*)g,
      (__attribute__((address_space(3))) unsigned int*)lds,
      16, 0, 0);
}

// ---- kernel 1: row L2 norm + normalize + cast to fp8 e4m3 (both inputs) -----
// one wave per row; 768 floats = 64 lanes x 3 float4 -> 12 fp8 bytes/lane
// row output = 192 dwords; lane writes dwords {lane, lane+64, lane+128}.

__global__ __launch_bounds__(256) void norm_cast_kernel(
    const float* __restrict__ EX, const float* __restrict__ EY,
    unsigned int* __restrict__ XO, unsigned int* __restrict__ YO, int Nx) {
  int row = blockIdx.x * 4 + (threadIdx.x >> 6);
  int lane = threadIdx.x & 63;
  const float* X = (row < Nx) ? EX : EY;
  unsigned int* Y = (row < Nx) ? XO : YO;
  int r = (row < Nx) ? row : (row - Nx);
  const float4* xr = (const float4*)(X + (size_t)r * D_DIM);
  float4 a = xr[lane];
  float4 b = xr[lane + 64];
  float4 c = xr[lane + 128];
  float ss = a.x*a.x + a.y*a.y + a.z*a.z + a.w*a.w
           + b.x*b.x + b.y*b.y + b.z*b.z + b.w*b.w
           + c.x*c.x + c.y*c.y + c.z*c.z + c.w*c.w;
  #pragma unroll
  for (int off = 32; off > 0; off >>= 1) ss += __shfl_xor(ss, off, 64);
  float s = 1.0f / fmaxf(sqrtf(ss), 1e-8f);
  unsigned int* yr = Y + (size_t)r * (D_DIM / 4);
  int d;
  d = __builtin_amdgcn_cvt_pk_fp8_f32(a.x * s, a.y * s, 0, false);
  d = __builtin_amdgcn_cvt_pk_fp8_f32(a.z * s, a.w * s, d, true);
  yr[lane] = (unsigned int)d;
  d = __builtin_amdgcn_cvt_pk_fp8_f32(b.x * s, b.y * s, 0, false);
  d = __builtin_amdgcn_cvt_pk_fp8_f32(b.z * s, b.w * s, d, true);
  yr[lane + 64] = (unsigned int)d;
  d = __builtin_amdgcn_cvt_pk_fp8_f32(c.x * s, c.y * s, 0, false);
  d = __builtin_amdgcn_cvt_pk_fp8_f32(c.z * s, c.w * s, d, true);
  yr[lane + 128] = (unsigned int)d;
}

// ---- kernel 2: MX-fp8 MFMA GEMM (S = A . B^T) fused with per-row max --------
// Block tile 128x256, BK=128 -> 6 K-iterations (768/128), 6 barriers total.
// 256 threads = 4 waves in 2x2; wave tile 64x128 = 2x4 grid of 32x32 tiles,
// 2 K=64 MFMA steps per K-tile -> 16 mfma_scale_f32_32x32x64_f8f6f4 / barrier.
// LDS rows = 128 B (8 x 16B chunks), XOR-swizzled: phys chunk = j ^ (row&7).
// Deposit (global_load_lds, 1024 B = 8 rows): lane -> row lane>>3, phys lane&7,
// so the lane fetches global chunk (lane&7) ^ ((lane>>3)&7).
// Fragment reads: 8-lane phases cover all 32 banks (conflict-free).

__global__ __launch_bounds__(256) void gemm_max_kernel(
    const unsigned char* __restrict__ A,   // exn [Nx x 768] fp8
    const unsigned char* __restrict__ B,   // eyn [Ny x 768] fp8
    float* __restrict__ partial,           // [ncb][Nx]
    int Nx) {
  __shared__ unsigned char As[BM * BK];   // 16 KB
  __shared__ unsigned char Bs[BN * BK];   // 32 KB
  __shared__ float red[2][BM];            // 1 KB

  const int tid  = threadIdx.x;
  const int wave = tid >> 6;
  const int lane = tid & 63;
  const int wm = wave >> 1;        // 0..1: row half (64 rows)
  const int wn = wave & 1;         // 0..1: col half (128 cols)
  const int l31 = lane & 31;
  const int h   = lane >> 5;       // half-wave: k-block selector
  const int skey = l31 & 7;        // reader-side swizzle key

  const int bm0 = blockIdx.x * BM;
  const int bn0 = blockIdx.y * BN;

  floatx16 acc[2][4];
  #pragma unroll
  for (int mt = 0; mt < 2; ++mt)
    #pragma unroll
    for (int nt = 0; nt < 4; ++nt)
      acc[mt][nt] = (floatx16)(0.f);

  // staging addresses: instr covers 8 rows x 128 B; lane -> row lane>>3,
  // phys chunk lane&7, global chunk (lane&7)^((lane>>3)&7)
  const int srow = lane >> 3;
  const int sj = (lane & 7) ^ (srow & 7);
  const unsigned char* gA = A + (size_t)(bm0 + wave * 32 + srow) * D_DIM + sj * 16;
  const unsigned char* gB = B + (size_t)(bn0 + wave * 64 + srow) * D_DIM + sj * 16;
  unsigned char* lA0 = As + (size_t)(wave * 32) * BK;  // wave stages 32 A rows (4 instrs)
  unsigned char* lB0 = Bs + (size_t)(wave * 64) * BK;  // and 64 B rows (8 instrs)
  const size_t g8 = (size_t)8 * D_DIM;                 // 8 global rows

  for (int k0 = 0; k0 < D_DIM; k0 += BK) {
    __syncthreads();  // previous tile fully consumed
    #pragma unroll
    for (int i = 0; i < 4; ++i)
      lds_load16(gA + k0 + i * g8, lA0 + i * 1024);
    #pragma unroll
    for (int i = 0; i < 8; ++i)
      lds_load16(gB + k0 + i * g8, lB0 + i * 1024);
    __syncthreads();  // staging visible

    #pragma unroll
    for (int ks = 0; ks < 2; ++ks) {     // two K=64 MFMA steps
      const int c0 = ks * 4 + 2 * h;     // logical 16B chunk pair {c0, c0+1}
      intx8 af[2], bf[4];
      #pragma unroll
      for (int mt = 0; mt < 2; ++mt) {
        const unsigned char* p = As + (size_t)(wm * 64 + mt * 32 + l31) * BK;
        int4 lo = *(const int4*)(p + (size_t)(c0 ^ skey) * 16);
        int4 hi = *(const int4*)(p + (size_t)((c0 + 1) ^ skey) * 16);
        af[mt] = (intx8){lo.x, lo.y, lo.z, lo.w, hi.x, hi.y, hi.z, hi.w};
      }
      #pragma unroll
      for (int nt = 0; nt < 4; ++nt) {
        const unsigned char* p = Bs + (size_t)(wn * 128 + nt * 32 + l31) * BK;
        int4 lo = *(const int4*)(p + (size_t)(c0 ^ skey) * 16);
        int4 hi = *(const int4*)(p + (size_t)((c0 + 1) ^ skey) * 16);
        bf[nt] = (intx8){lo.x, lo.y, lo.z, lo.w, hi.x, hi.y, hi.z, hi.w};
      }
      #pragma unroll
      for (int mt = 0; mt < 2; ++mt)
        #pragma unroll
        for (int nt = 0; nt < 4; ++nt)
          acc[mt][nt] = __builtin_amdgcn_mfma_scale_f32_32x32x64_f8f6f4(
              af[mt], bf[nt], acc[mt][nt],
              0, 0,                    // cbsz=fp8(e4m3), blgp=fp8(e4m3)
              0, SCALE_ONE,            // A scale: opsel 0, E8M0 unit
              0, SCALE_ONE);           // B scale
    }
  }

  // epilogue: per-row max over this block's 256 columns.
  // C/D (32x32): col = l31 (+nt*32 + wn*128), row = (reg&3)+8*(reg>>2)+4*h (+mt*32+wm*64)
  #pragma unroll
  for (int mt = 0; mt < 2; ++mt) {
    #pragma unroll
    for (int reg = 0; reg < 16; ++reg) {
      float v = fmaxf(fmaxf(acc[mt][0][reg], acc[mt][1][reg]),
                      fmaxf(acc[mt][2][reg], acc[mt][3][reg]));
      #pragma unroll
      for (int off = 1; off < 32; off <<= 1)
        v = fmaxf(v, __shfl_xor(v, off, 64));   // reduce over l31 within each half
      if (l31 == 0) {
        int r = wm * 64 + mt * 32 + (reg & 3) + 8 * (reg >> 2) + 4 * h;
        red[wn][r] = v;
      }
    }
  }
  __syncthreads();
  if (tid < BM) {
    float m = fmaxf(red[0][tid], red[1][tid]);
    partial[(size_t)blockIdx.y * Nx + bm0 + tid] = m;
  }
}

// ---- kernel 3: row max over column blocks + halfnormal transform + block sum

__global__ __launch_bounds__(256) void rowmax_kernel(
    const float* __restrict__ partial, float* __restrict__ bsum, int Nx, int ncb) {
  __shared__ float sdata[4];
  int r = blockIdx.x * blockDim.x + threadIdx.x;
  float m = -1e30f;
  for (int cb = 0; cb < ncb; ++cb)
    m = fmaxf(m, partial[(size_t)cb * Nx + r]);
  float x = 1.0f - m;
  const float logc = -0.22579135264472744f;  // 0.5*log(2/pi), sigma=1
  float l = logc - 0.5f * x * x;
  float t = -__expf(l) * l;
  #pragma unroll
  for (int off = 32; off > 0; off >>= 1) t += __shfl_xor(t, off, 64);
  int wave = threadIdx.x >> 6;
  int lane = threadIdx.x & 63;
  if (lane == 0) sdata[wave] = t;
  __syncthreads();
  if (threadIdx.x == 0)
    bsum[blockIdx.x] = sdata[0] + sdata[1] + sdata[2] + sdata[3];
}

// ---- kernel 4: final sum of block partials -> out[0], out[1] ----------------

__global__ __launch_bounds__(64) void final_kernel(
    const float* __restrict__ bsum, float* __restrict__ out, int nb) {
  int lane = threadIdx.x;
  float s = (lane < nb) ? bsum[lane] : 0.f;
  #pragma unroll
  for (int off = 32; off > 0; off >>= 1) s += __shfl_xor(s, off, 64);
  if (lane == 0) { out[0] = s; out[1] = s; }
}

// ---- launch -----------------------------------------------------------------

extern "C" void kernel_launch(void* const* d_in, const int* in_sizes, int n_in,
                              void* d_out, int out_size, void* d_ws, size_t ws_size,
                              hipStream_t stream) {
  const float* ex = (const float*)d_in[0];
  const float* ey = (const float*)d_in[1];
  const int Nx = in_sizes[0] / D_DIM;   // 8192
  const int Ny = in_sizes[1] / D_DIM;   // 16384
  const int ncb = Ny / BN;              // 64

  char* ws = (char*)d_ws;
  unsigned char* exn = (unsigned char*)ws;                                   // Nx*768 fp8
  unsigned char* eyn = exn + (size_t)Nx * D_DIM;                             // Ny*768 fp8
  float* partial = (float*)(ws + (size_t)(Nx + Ny) * D_DIM);                 // ncb*Nx f32
  float* bsum    = partial + (size_t)ncb * Nx;                               // 32 f32

  norm_cast_kernel<<<(Nx + Ny) / 4, 256, 0, stream>>>(
      ex, ey, (unsigned int*)exn, (unsigned int*)eyn, Nx);
  gemm_max_kernel<<<dim3(Nx / BM, Ny / BN), 256, 0, stream>>>(exn, eyn, partial, Nx);
  rowmax_kernel<<<Nx / 256, 256, 0, stream>>>(partial, bsum, Nx, ncb);
  final_kernel<<<1, 64, 0, stream>>>(bsum, (float*)d_out, Nx / 256);
}

// Round 4
// 251.408 us; speedup vs baseline: 1.8371x; 1.8371x over previous
//
#include <hip/hip_runtime.h>
#include <hip/hip_bf16.h>
#include <cstdint>

#define D_DIM 768
#define BM 128
#define BN 256
#define BK 128   // one K-tile = 2 k-steps of the K=64 MFMA

typedef int   intx8    __attribute__((ext_vector_type(8)));
typedef float floatx16 __attribute__((ext_vector_type(16)));

#define SCALE_ONE 0x7F7F7F7F  // E8M0 127 = 2^0 in every byte

// ---- helpers ----------------------------------------------------------------

__device__ inline void lds_load16(const void* g, void* lds) {
  __builtin_amdgcn_global_load_lds(
      (const __attribute__((address_space(1))) unsigned int*)g,
      (__attribute__((address_space(3))) unsigned int*)lds,
      16, 0, 0);
}

__device__ inline intx8 ldfrag(const unsigned char* p, int o0, int o1) {
  intx8 r;
  *(int4*)&r       = *(const int4*)(p + o0);
  *((int4*)&r + 1) = *(const int4*)(p + o1);
  return r;
}

// ---- kernel 1: row L2 norm + normalize + cast to fp8 e4m3 (both inputs) -----

__global__ __launch_bounds__(256) void norm_cast_kernel(
    const float* __restrict__ EX, const float* __restrict__ EY,
    unsigned int* __restrict__ XO, unsigned int* __restrict__ YO, int Nx) {
  int row = blockIdx.x * 4 + (threadIdx.x >> 6);
  int lane = threadIdx.x & 63;
  const float* X = (row < Nx) ? EX : EY;
  unsigned int* Y = (row < Nx) ? XO : YO;
  int r = (row < Nx) ? row : (row - Nx);
  const float4* xr = (const float4*)(X + (size_t)r * D_DIM);
  float4 a = xr[lane];
  float4 b = xr[lane + 64];
  float4 c = xr[lane + 128];
  float ss = a.x*a.x + a.y*a.y + a.z*a.z + a.w*a.w
           + b.x*b.x + b.y*b.y + b.z*b.z + b.w*b.w
           + c.x*c.x + c.y*c.y + c.z*c.z + c.w*c.w;
  #pragma unroll
  for (int off = 32; off > 0; off >>= 1) ss += __shfl_xor(ss, off, 64);
  float s = 1.0f / fmaxf(sqrtf(ss), 1e-8f);
  unsigned int* yr = Y + (size_t)r * (D_DIM / 4);
  int d;
  d = __builtin_amdgcn_cvt_pk_fp8_f32(a.x * s, a.y * s, 0, false);
  d = __builtin_amdgcn_cvt_pk_fp8_f32(a.z * s, a.w * s, d, true);
  yr[lane] = (unsigned int)d;
  d = __builtin_amdgcn_cvt_pk_fp8_f32(b.x * s, b.y * s, 0, false);
  d = __builtin_amdgcn_cvt_pk_fp8_f32(b.z * s, b.w * s, d, true);
  yr[lane + 64] = (unsigned int)d;
  d = __builtin_amdgcn_cvt_pk_fp8_f32(c.x * s, c.y * s, 0, false);
  d = __builtin_amdgcn_cvt_pk_fp8_f32(c.z * s, c.w * s, d, true);
  yr[lane + 128] = (unsigned int)d;
}

// ---- kernel 2: MX-fp8 MFMA GEMM (S = A . B^T) fused with per-row max --------
// Block tile 128x256, BK=128 -> 6 K-iterations / 6 barriers. 256 threads =
// 4 waves in 2x2; wave tile 64x128 = 2x4 grid of 32x32, 2 K=64 steps/tile ->
// 16 mfma_scale per barrier. LDS rows 128 B, 16B chunks swizzled
// phys = j ^ (row&7); deposit via global_load_lds (lane -> row lane>>3,
// phys lane&7 -> global chunk (lane&7)^((lane>>3)&7)).
// R3 lesson: without the min-waves bound this spills (460 MB scratch writes);
// (256,2) + interleaved frag loads keeps live set ~180 regs.

__global__ __launch_bounds__(256, 2) void gemm_max_kernel(
    const unsigned char* __restrict__ A,   // exn [Nx x 768] fp8
    const unsigned char* __restrict__ B,   // eyn [Ny x 768] fp8
    float* __restrict__ partial,           // [ncb][Nx]
    int Nx) {
  __shared__ unsigned char As[BM * BK];   // 16 KB
  __shared__ unsigned char Bs[BN * BK];   // 32 KB
  __shared__ float red[2][BM];            // 1 KB

  const int tid  = threadIdx.x;
  const int wave = tid >> 6;
  const int lane = tid & 63;
  const int wm = wave >> 1;        // 0..1: row half (64 rows)
  const int wn = wave & 1;         // 0..1: col half (128 cols)
  const int l31 = lane & 31;
  const int h   = lane >> 5;       // half-wave: k-block selector
  const int skey = l31 & 7;        // reader-side swizzle key

  const int bm0 = blockIdx.x * BM;
  const int bn0 = blockIdx.y * BN;

  floatx16 acc[2][4];
  #pragma unroll
  for (int mt = 0; mt < 2; ++mt)
    #pragma unroll
    for (int nt = 0; nt < 4; ++nt)
      acc[mt][nt] = (floatx16)(0.f);

  // loop-invariant LDS row bases (chunk offsets vary inside the loop)
  const unsigned char* pA0 = As + (size_t)(wm * 64 + 0  + l31) * BK;
  const unsigned char* pA1 = As + (size_t)(wm * 64 + 32 + l31) * BK;
  const unsigned char* pB0 = Bs + (size_t)(wn * 128 + 0   + l31) * BK;
  const unsigned char* pB1 = Bs + (size_t)(wn * 128 + 32  + l31) * BK;
  const unsigned char* pB2 = Bs + (size_t)(wn * 128 + 64  + l31) * BK;
  const unsigned char* pB3 = Bs + (size_t)(wn * 128 + 96  + l31) * BK;

  // staging addresses
  const int srow = lane >> 3;
  const int sj = (lane & 7) ^ (srow & 7);
  const unsigned char* gA = A + (size_t)(bm0 + wave * 32 + srow) * D_DIM + sj * 16;
  const unsigned char* gB = B + (size_t)(bn0 + wave * 64 + srow) * D_DIM + sj * 16;
  unsigned char* lA0 = As + (size_t)(wave * 32) * BK;  // wave stages 32 A rows
  unsigned char* lB0 = Bs + (size_t)(wave * 64) * BK;  // and 64 B rows
  const size_t g8 = (size_t)8 * D_DIM;                 // 8 global rows

  for (int k0 = 0; k0 < D_DIM; k0 += BK) {
    __syncthreads();  // previous tile fully consumed
    #pragma unroll
    for (int i = 0; i < 4; ++i)
      lds_load16(gA + k0 + i * g8, lA0 + i * 1024);
    #pragma unroll
    for (int i = 0; i < 8; ++i)
      lds_load16(gB + k0 + i * g8, lB0 + i * 1024);
    __syncthreads();  // staging visible

    #pragma unroll
    for (int ks = 0; ks < 2; ++ks) {     // two K=64 MFMA steps
      const int c0 = ks * 4 + 2 * h;     // logical 16B chunk pair {c0, c0+1}
      const int o0 = (c0 ^ skey) * 16;
      const int o1 = ((c0 + 1) ^ skey) * 16;
      intx8 a0 = ldfrag(pA0, o0, o1);
      intx8 a1 = ldfrag(pA1, o0, o1);
      intx8 b;
      b = ldfrag(pB0, o0, o1);
      acc[0][0] = __builtin_amdgcn_mfma_scale_f32_32x32x64_f8f6f4(
          a0, b, acc[0][0], 0, 0, 0, SCALE_ONE, 0, SCALE_ONE);
      acc[1][0] = __builtin_amdgcn_mfma_scale_f32_32x32x64_f8f6f4(
          a1, b, acc[1][0], 0, 0, 0, SCALE_ONE, 0, SCALE_ONE);
      b = ldfrag(pB1, o0, o1);
      acc[0][1] = __builtin_amdgcn_mfma_scale_f32_32x32x64_f8f6f4(
          a0, b, acc[0][1], 0, 0, 0, SCALE_ONE, 0, SCALE_ONE);
      acc[1][1] = __builtin_amdgcn_mfma_scale_f32_32x32x64_f8f6f4(
          a1, b, acc[1][1], 0, 0, 0, SCALE_ONE, 0, SCALE_ONE);
      b = ldfrag(pB2, o0, o1);
      acc[0][2] = __builtin_amdgcn_mfma_scale_f32_32x32x64_f8f6f4(
          a0, b, acc[0][2], 0, 0, 0, SCALE_ONE, 0, SCALE_ONE);
      acc[1][2] = __builtin_amdgcn_mfma_scale_f32_32x32x64_f8f6f4(
          a1, b, acc[1][2], 0, 0, 0, SCALE_ONE, 0, SCALE_ONE);
      b = ldfrag(pB3, o0, o1);
      acc[0][3] = __builtin_amdgcn_mfma_scale_f32_32x32x64_f8f6f4(
          a0, b, acc[0][3], 0, 0, 0, SCALE_ONE, 0, SCALE_ONE);
      acc[1][3] = __builtin_amdgcn_mfma_scale_f32_32x32x64_f8f6f4(
          a1, b, acc[1][3], 0, 0, 0, SCALE_ONE, 0, SCALE_ONE);
    }
  }

  // epilogue: per-row max over this block's 256 columns.
  // C/D (32x32): col = l31 (+nt*32 + wn*128), row = (reg&3)+8*(reg>>2)+4*h (+mt*32+wm*64)
  #pragma unroll
  for (int mt = 0; mt < 2; ++mt) {
    #pragma unroll
    for (int reg = 0; reg < 16; ++reg) {
      float v = fmaxf(fmaxf(acc[mt][0][reg], acc[mt][1][reg]),
                      fmaxf(acc[mt][2][reg], acc[mt][3][reg]));
      #pragma unroll
      for (int off = 1; off < 32; off <<= 1)
        v = fmaxf(v, __shfl_xor(v, off, 64));   // reduce over l31 within each half
      if (l31 == 0) {
        int r = wm * 64 + mt * 32 + (reg & 3) + 8 * (reg >> 2) + 4 * h;
        red[wn][r] = v;
      }
    }
  }
  __syncthreads();
  if (tid < BM) {
    float m = fmaxf(red[0][tid], red[1][tid]);
    partial[(size_t)blockIdx.y * Nx + bm0 + tid] = m;
  }
}

// ---- kernel 3: row max over column blocks + halfnormal transform + block sum

__global__ __launch_bounds__(256) void rowmax_kernel(
    const float* __restrict__ partial, float* __restrict__ bsum, int Nx, int ncb) {
  __shared__ float sdata[4];
  int r = blockIdx.x * blockDim.x + threadIdx.x;
  float m = -1e30f;
  for (int cb = 0; cb < ncb; ++cb)
    m = fmaxf(m, partial[(size_t)cb * Nx + r]);
  float x = 1.0f - m;
  const float logc = -0.22579135264472744f;  // 0.5*log(2/pi), sigma=1
  float l = logc - 0.5f * x * x;
  float t = -__expf(l) * l;
  #pragma unroll
  for (int off = 32; off > 0; off >>= 1) t += __shfl_xor(t, off, 64);
  int wave = threadIdx.x >> 6;
  int lane = threadIdx.x & 63;
  if (lane == 0) sdata[wave] = t;
  __syncthreads();
  if (threadIdx.x == 0)
    bsum[blockIdx.x] = sdata[0] + sdata[1] + sdata[2] + sdata[3];
}

// ---- kernel 4: final sum of block partials -> out[0], out[1] ----------------

__global__ __launch_bounds__(64) void final_kernel(
    const float* __restrict__ bsum, float* __restrict__ out, int nb) {
  int lane = threadIdx.x;
  float s = (lane < nb) ? bsum[lane] : 0.f;
  #pragma unroll
  for (int off = 32; off > 0; off >>= 1) s += __shfl_xor(s, off, 64);
  if (lane == 0) { out[0] = s; out[1] = s; }
}

// ---- launch -----------------------------------------------------------------

extern "C" void kernel_launch(void* const* d_in, const int* in_sizes, int n_in,
                              void* d_out, int out_size, void* d_ws, size_t ws_size,
                              hipStream_t stream) {
  const float* ex = (const float*)d_in[0];
  const float* ey = (const float*)d_in[1];
  const int Nx = in_sizes[0] / D_DIM;   // 8192
  const int Ny = in_sizes[1] / D_DIM;   // 16384
  const int ncb = Ny / BN;              // 64

  char* ws = (char*)d_ws;
  unsigned char* exn = (unsigned char*)ws;                                   // Nx*768 fp8
  unsigned char* eyn = exn + (size_t)Nx * D_DIM;                             // Ny*768 fp8
  float* partial = (float*)(ws + (size_t)(Nx + Ny) * D_DIM);                 // ncb*Nx f32
  float* bsum    = partial + (size_t)ncb * Nx;                               // 32 f32

  norm_cast_kernel<<<(Nx + Ny) / 4, 256, 0, stream>>>(
      ex, ey, (unsigned int*)exn, (unsigned int*)eyn, Nx);
  gemm_max_kernel<<<dim3(Nx / BM, Ny / BN), 256, 0, stream>>>(exn, eyn, partial, Nx);
  rowmax_kernel<<<Nx / 256, 256, 0, stream>>>(partial, bsum, Nx, ncb);
  final_kernel<<<1, 64, 0, stream>>>(bsum, (float*)d_out, Nx / 256);
}